// Round 5
// baseline (1729.897 us; speedup 1.0000x reference)
//
#include <hip/hip_runtime.h>

// LSTM net: linear1(20->50) -> 3x LSTMCell(50) (reference's buggy c-flow)
//   -> linear2(50->8).  B=512, T=1024.
//
// 256 blocks x 512 threads (8 waves), 1 block/CU, 2 batch elems/block.
// WHY 512: r1-r3 showed any block >8 waves forces 3 waves/SIMD -> 170
// unified regs/wave -> weight arrays park in AGPRs (VGPR_Count pinned at
// ~76) and every weight use pays v_accvgpr_read.  8 waves -> 2/SIMD ->
// 256 regs/wave; per-lane demand ~185 stays arch-resident.
//
// Proven r3 primitives kept verbatim: octet [L2 quad | L3 quad] with
// swzx4 P3->L2 same-step handoff (reference's c2<-cell3 bug), i/f/g/o row
// order, DPP quad_perm reduce, linear1 folded into L1 (Wfold = Wih1@W1).
//
// New: uniform 18-iter gate loop for ALL 500 gate lanes (zero-pad weights)
// so mixed-role waves pay one path; combined LDS buffer C[q] = [x(t), t&1=q
// | h1(t'), (t'+1)&1=q | pad] gives L1 pairs a single base pointer.
//
// Lane map: tid 0-399   octets (u=tid>>3): loc 0-3 L2 quad, 4-7 L3 quad,
//                        lane r=loc&3: side=r>>1 (in/rec), chunk=r&1 (26 dims)
//           tid 400-499 L1 pairs (u=(tid-400)>>1): lane h owns concat dims
//                        36h..36h+35 of [foldedX(20) | h1(50) | pad]
//           tid 500-507 out-proj (ok=tid-500, both batches via pk)
//           tid 508-511 x-stage (4 lanes x 5 dims, stride 4; 1-step prefetch)
// Step s: L1 t=s, L2 t=s-1, L3 t=s-2, out t=s-3.

#define T_SEQ 1024
#define IN_DIM 20
#define OUT_DIM 8

// LDS f32x2 ({batch0,batch1}) offsets
#define XC   0      // C [2][88]: 0-19 x, 20-69 h1, 70-87 pad0
#define XH2  176    // h2 [2][64] (50 used, pad0)
#define XH3  304    // h3 [2][64]
#define SMSZ 432

typedef float f32x2 __attribute__((ext_vector_type(2)));
typedef float f32x4 __attribute__((ext_vector_type(4)));

// d += broadcast(w.lo)*u  /  d += broadcast(w.hi)*u   (VOP3P op_sel)
__device__ __forceinline__ void pkfma_lo(f32x2& d, f32x2 w, f32x2 u) {
    asm("v_pk_fma_f32 %0, %1, %2, %0 op_sel:[0,0,0] op_sel_hi:[0,1,1]"
        : "+v"(d) : "v"(w), "v"(u));
}
__device__ __forceinline__ void pkfma_hi(f32x2& d, f32x2 w, f32x2 u) {
    asm("v_pk_fma_f32 %0, %1, %2, %0 op_sel:[1,0,0] op_sel_hi:[1,1,1]"
        : "+v"(d) : "v"(w), "v"(u));
}
__device__ __forceinline__ void pkfma(f32x2& d, f32x2 a, f32x2 b) {
    asm("v_pk_fma_f32 %0, %1, %2, %0" : "+v"(d) : "v"(a), "v"(b));
}
__device__ __forceinline__ float sigm(float x) {
    return __builtin_amdgcn_rcpf(1.0f + __expf(-x));
}
__device__ __forceinline__ float tanh_f(float x) {
    return fmaf(2.0f, sigm(2.0f * x), -1.0f);
}
__device__ __forceinline__ f32x2 sigm2(f32x2 v, float b) {
    f32x2 r; r.x = sigm(v.x + b); r.y = sigm(v.y + b); return r;
}
__device__ __forceinline__ f32x2 tanh2(f32x2 v, float b) {
    f32x2 r; r.x = tanh_f(v.x + b); r.y = tanh_f(v.y + b); return r;
}
template <int CTRL>   // quad_perm DPP: 0xB1 = lane^1, 0x4E = lane^2
__device__ __forceinline__ f32x2 dpp2(f32x2 v) {
    f32x2 r;
    r.x = __int_as_float(__builtin_amdgcn_mov_dpp(__float_as_int(v.x), CTRL, 0xF, 0xF, true));
    r.y = __int_as_float(__builtin_amdgcn_mov_dpp(__float_as_int(v.y), CTRL, 0xF, 0xF, true));
    return r;
}
__device__ __forceinline__ f32x2 swzx4(f32x2 v) {   // lane ^ 4 (bit-mode)
    f32x2 r;
    r.x = __int_as_float(__builtin_amdgcn_ds_swizzle(__float_as_int(v.x), 0x101F));
    r.y = __int_as_float(__builtin_amdgcn_ds_swizzle(__float_as_int(v.y), 0x101F));
    return r;
}

__global__ __launch_bounds__(512, 2) void lstm_net_kernel(
    const float* __restrict__ x,
    const float* __restrict__ W1,   const float* __restrict__ b1,
    const float* __restrict__ Wih1, const float* __restrict__ Whh1,
    const float* __restrict__ bih1, const float* __restrict__ bhh1,
    const float* __restrict__ Wih2, const float* __restrict__ Whh2,
    const float* __restrict__ bih2, const float* __restrict__ bhh2,
    const float* __restrict__ Wih3, const float* __restrict__ Whh3,
    const float* __restrict__ bih3, const float* __restrict__ bhh3,
    const float* __restrict__ W2,   const float* __restrict__ b2,
    float* __restrict__ out)
{
    __shared__ __align__(16) f32x2 sm2[SMSZ];

    const int tid = threadIdx.x;
    const int b0  = blockIdx.x * 2;

    for (int i = tid; i < SMSZ; i += 512) sm2[i] = (f32x2){0.f, 0.f};
    __syncthreads();

    f32x2 wv[72];                        // 4 gates x 18 weight pairs
    #pragma unroll
    for (int i = 0; i < 72; i++) wv[i] = (f32x2){0.f, 0.f};
    float bias4[4] = {0.f, 0.f, 0.f, 0.f};
    int   sel = 0, boff = 0, u = 0, loc = 0, ok = 0, sd = 0;
    bool  isOct = false, isL3 = false;
    f32x2 c1 = {0.f, 0.f};               // L1 cell (even L1 lanes)
    f32x2 xs[5];
    #pragma unroll
    for (int i = 0; i < 5; i++) xs[i] = (f32x2){0.f, 0.f};

    if (tid < 400) {                     // L2/L3 octets (r3-proven)
        isOct = true;
        u = tid >> 3; loc = tid & 7; isL3 = (loc >= 4);
        const int r = loc & 3, side = r >> 1, chunk = r & 1;
        const float* src = isL3 ? (side ? Whh3 : Wih3) : (side ? Whh2 : Wih2);
        const float* bi  = isL3 ? bih3 : bih2;
        const float* bh  = isL3 ? bhh3 : bhh2;
        const int row4[4] = {u, 50 + u, 100 + u, 150 + u};   // i,f,g,o
        #pragma unroll
        for (int m = 0; m < 4; m++) {
            const bool dead = isL3 && (m == 1);              // f3 dead (c3==0)
            const int row = row4[m];
            #pragma unroll
            for (int i = 0; i < 18; i++) {
                const int k0 = 2 * i, k1 = 2 * i + 1;
                const int d0 = 26 * chunk + k0, d1 = 26 * chunk + k1;
                const float w0 = (!dead && k0 < 26 && d0 < 50) ? src[row * 50 + d0] : 0.f;
                const float w1 = (!dead && k1 < 26 && d1 < 50) ? src[row * 50 + d1] : 0.f;
                wv[m * 18 + i] = (f32x2){w0, w1};
            }
            bias4[m] = dead ? 0.f : bi[row] + bh[row];
        }
        if (!isL3) { sel = side ? 1 : 0; boff = side ? 26 * chunk : 20 + 26 * chunk; }
        else       { sel = side ? 2 : 1; boff = 26 * chunk; }
    } else if (tid < 500) {              // L1 pairs, linear1 folded
        u = (tid - 400) >> 1;
        const int h = tid & 1;           // tid 400 even -> lane-aligned pairs
        sel = 0; boff = 36 * h;
        const int row4[4] = {u, 50 + u, 100 + u, 150 + u};
        #pragma unroll
        for (int m = 0; m < 4; m++) {
            const int row = row4[m];
            float bs = bih1[row] + bhh1[row];
            for (int j = 0; j < 50; j++) bs = fmaf(Wih1[row * 50 + j], b1[j], bs);
            bias4[m] = bs;
            if (h == 0) {                // concat dims 0-35 = foldedX(20)+h1(0-15)
                float a20[20];
                #pragma unroll
                for (int k = 0; k < 20; k++) a20[k] = 0.f;
                for (int j = 0; j < 50; j++) {
                    const float a = Wih1[row * 50 + j];
                    const float* w1r = W1 + j * 20;
                    #pragma unroll
                    for (int k = 0; k < 20; k++) a20[k] = fmaf(a, w1r[k], a20[k]);
                }
                #pragma unroll
                for (int i = 0; i < 18; i++) {
                    const int k0 = 2 * i, k1 = 2 * i + 1;
                    const float w0 = (k0 < 20) ? a20[k0] : Whh1[row * 50 + (k0 - 20)];
                    const float w1 = (k1 < 20) ? a20[k1] : Whh1[row * 50 + (k1 - 20)];
                    wv[m * 18 + i] = (f32x2){w0, w1};
                }
            } else {                     // concat dims 36-71 = h1(16-49)+pad
                #pragma unroll
                for (int i = 0; i < 18; i++) {
                    const int k0 = 2 * i, k1 = 2 * i + 1;
                    const float w0 = (k0 < 34) ? Whh1[row * 50 + 16 + k0] : 0.f;
                    const float w1 = (k1 < 34) ? Whh1[row * 50 + 16 + k1] : 0.f;
                    wv[m * 18 + i] = (f32x2){w0, w1};
                }
            }
        }
    } else if (tid < 508) {              // out-proj
        ok = tid - 500;
        #pragma unroll
        for (int i = 0; i < 26; i++) {
            const int d0 = 2 * i, d1 = 2 * i + 1;
            const float w0 = (d0 < 50) ? W2[ok * 50 + d0] : 0.f;
            const float w1 = (d1 < 50) ? W2[ok * 50 + d1] : 0.f;
            wv[i] = (f32x2){w0, w1};
        }
        bias4[0] = b2[ok];
    } else {                             // x-stage: 4 lanes x dims {sd+4i}
        sd = tid - 508;
        for (int t = 0; t < 3; t++) {    // x(0)->C[0], x(1)->C[1], x(2)->regs
            #pragma unroll
            for (int i = 0; i < 5; i++) {
                const int dim = sd + 4 * i;
                f32x2 v;
                v.x = x[((size_t)b0 * T_SEQ + t) * IN_DIM + dim];
                v.y = x[((size_t)(b0 + 1) * T_SEQ + t) * IN_DIM + dim];
                if (t < 2) sm2[XC + t * 88 + dim] = v;
                else       xs[i] = v;
            }
        }
    }
    __syncthreads();

    for (int s = 0; s < T_SEQ + 3; ++s) {
        const int p = s & 1, pm = p ^ 1;

        if (tid < 500) {                 // uniform gate path (octets + L1)
            const int base = ((sel == 0) ? (XC + p * 88)
                            : (sel == 1) ? (XH2 + p * 64)
                                         : (XH3 + pm * 64)) + boff;
            const f32x4* B4 = (const f32x4*)(sm2 + base);
            f32x2 A0 = {0.f,0.f}, A1 = {0.f,0.f}, A2 = {0.f,0.f}, A3 = {0.f,0.f};
            #pragma unroll
            for (int i = 0; i < 18; i++) {
                const f32x4 uu = B4[i];
                const f32x2 ul = uu.lo, uh = uu.hi;
                pkfma_lo(A0, wv[i],      ul); pkfma_hi(A0, wv[i],      uh);
                pkfma_lo(A1, wv[18 + i], ul); pkfma_hi(A1, wv[18 + i], uh);
                pkfma_lo(A2, wv[36 + i], ul); pkfma_hi(A2, wv[36 + i], uh);
                pkfma_lo(A3, wv[54 + i], ul); pkfma_hi(A3, wv[54 + i], uh);
            }
            A0 += dpp2<0xB1>(A0); A1 += dpp2<0xB1>(A1);
            A2 += dpp2<0xB1>(A2); A3 += dpp2<0xB1>(A3);
            if (isOct) {                 // octets: full quad allreduce
                A0 += dpp2<0x4E>(A0); A1 += dpp2<0x4E>(A1);
                A2 += dpp2<0x4E>(A2); A3 += dpp2<0x4E>(A3);
            }
            const f32x2 ii = sigm2(A0, bias4[0]);
            const f32x2 ff = sigm2(A1, bias4[1]);
            const f32x2 gg = tanh2(A2, bias4[2]);
            const f32x2 oo = sigm2(A3, bias4[3]);
            f32x2 P = ii * gg;

            if (isOct) {
                const bool valid3 = (s >= 2) && (s < T_SEQ + 2);
                f32x2 ps = P;
                if (isL3 && !valid3) ps = (f32x2){0.f, 0.f};
                const f32x2 t4 = swzx4(ps);          // L2 lanes receive P3
                if (loc == 0) {                      // L2 combine, t2 = s-1
                    if (s >= 1 && s <= T_SEQ) {
                        f32x2 c2 = P;                // P2
                        pkfma(c2, ff, t4);           // c2 = P2 + f2*P3
                        f32x2 hh;
                        hh.x = oo.x * tanh_f(c2.x);
                        hh.y = oo.y * tanh_f(c2.y);
                        sm2[XH2 + pm * 64 + u] = hh; // slot t2&1 = pm
                    }
                } else if (loc == 4) {               // L3 combine, t3 = s-2
                    if (valid3) {
                        f32x2 hh;
                        hh.x = oo.x * tanh_f(P.x);   // c3==0: cell = i3*g3
                        hh.y = oo.y * tanh_f(P.y);
                        sm2[XH3 + p * 64 + u] = hh;  // slot t3&1 = p
                    }
                }
            } else {                                 // L1 combine, t1 = s
                if ((tid & 1) == 0 && s < T_SEQ) {
                    f32x2 cn = P;
                    pkfma(cn, ff, c1);               // cn = i*g + f*c1
                    c1 = cn;
                    f32x2 hh;
                    hh.x = oo.x * tanh_f(c1.x);
                    hh.y = oo.y * tanh_f(c1.y);
                    sm2[XC + pm * 88 + 20 + u] = hh; // consumer-parity slot
                }
            }
        } else if (tid < 508) {          // out, t = s-3
            if (s >= 3) {
                const int t = s - 3;
                const f32x4* H4 = (const f32x4*)(sm2 + XH3 + pm * 64);
                f32x2 a0 = {0.f, 0.f}, a1 = {0.f, 0.f};
                #pragma unroll
                for (int i = 0; i < 26; i++) {
                    const f32x4 uu = H4[i];
                    pkfma_lo(a0, wv[i], uu.lo);
                    pkfma_hi(a1, wv[i], uu.hi);
                }
                const f32x2 acc = a0 + a1;
                out[((size_t)b0 * T_SEQ + t) * OUT_DIM + ok]       = acc.x + bias4[0];
                out[((size_t)(b0 + 1) * T_SEQ + t) * OUT_DIM + ok] = acc.y + bias4[0];
            }
        } else {                         // x-stage
            if (s >= 1 && s + 1 < T_SEQ) {           // commit x(s+1) -> C[pm]
                #pragma unroll
                for (int i = 0; i < 5; i++)
                    sm2[XC + pm * 88 + sd + 4 * i] = xs[i];
            }
            if (s + 2 < T_SEQ) {                     // load x(s+2) -> regs
                const int t = s + 2;
                #pragma unroll
                for (int i = 0; i < 5; i++) {
                    const int dim = sd + 4 * i;
                    xs[i].x = x[((size_t)b0 * T_SEQ + t) * IN_DIM + dim];
                    xs[i].y = x[((size_t)(b0 + 1) * T_SEQ + t) * IN_DIM + dim];
                }
            }
        }
        __syncthreads();
    }
}

extern "C" void kernel_launch(void* const* d_in, const int* in_sizes, int n_in,
                              void* d_out, int out_size, void* d_ws, size_t ws_size,
                              hipStream_t stream) {
    const float* x    = (const float*)d_in[0];
    const float* W1   = (const float*)d_in[1];
    const float* b1   = (const float*)d_in[2];
    const float* Wih1 = (const float*)d_in[3];
    const float* Whh1 = (const float*)d_in[4];
    const float* bih1 = (const float*)d_in[5];
    const float* bhh1 = (const float*)d_in[6];
    const float* Wih2 = (const float*)d_in[7];
    const float* Whh2 = (const float*)d_in[8];
    const float* bih2 = (const float*)d_in[9];
    const float* bhh2 = (const float*)d_in[10];
    const float* Wih3 = (const float*)d_in[11];
    const float* Whh3 = (const float*)d_in[12];
    const float* bih3 = (const float*)d_in[13];
    const float* bhh3 = (const float*)d_in[14];
    const float* W2   = (const float*)d_in[15];
    const float* b2   = (const float*)d_in[16];
    float* out = (float*)d_out;

    dim3 grid(256), block(512);
    lstm_net_kernel<<<grid, block, 0, stream>>>(
        x, W1, b1, Wih1, Whh1, bih1, bhh1, Wih2, Whh2, bih2, bhh2,
        Wih3, Whh3, bih3, bhh3, W2, b2, out);
}

// Round 7
// 1727.348 us; speedup vs baseline: 1.0015x; 1.0015x over previous
//
#include <hip/hip_runtime.h>

// LSTM net: linear1(20->50) -> 3x LSTMCell(50) (reference's buggy c-flow)
//   -> linear2(50->8).  B=512, T=1024.
//
// 256 blocks x 512 threads (8 waves = 2/SIMD), 1 block/CU, 2 batch/block.
// BASE = round-5 kernel (PASSED, 1729us) byte-identical in all windows,
// weights, parities.  Exactly two deltas (bisection after r6's 3-change
// failure):
//  1. amdgpu_waves_per_eu(2,2): pin occupancy so the allocator stops
//     targeting a higher default occupancy and parking the 144-float
//     weight array in AGPRs (r5: VGPR_Count=100 despite 256-reg budget;
//     ~370 excess VALU instrs/wave/step of v_accvgpr_read staging).
//  2. Bank-slot constants: C stride 88->96 (96/2%8==0: slot-invariant
//     across parity), XH2 176->192, XH3 304->322.  Octet broadcast
//     streams land on 16B-slots {2,7,0,5,1,6} (h1c0,h1c1,h2c0,h2c1,
//     h3c0,h3c1) - all distinct -> pure-octet waves conflict-free.
//     (r5: {2,7,0,5,0,5} + parity shift -> 1.23e8 conflicts.)
//
// Lane map: tid 0-399   octets (u=tid>>3): loc 0-3 L2 quad, 4-7 L3 quad;
//                        lane r=loc&3: side=r>>1 (in/rec), chunk=r&1
//           tid 400-499 L1 pairs (u=(tid-400)>>1), lane h: window 36h
//           tid 500-507 out-proj; tid 508-511 x-stage (4 lanes x 5 dims)
// Step s: L1 t=s, L2 t=s-1, L3 t=s-2 (P3 -> L2 same step via swzx4 =
//         reference's c2<-cell3 bug), out t=s-3.

#define T_SEQ 1024
#define IN_DIM 20
#define OUT_DIM 8

// LDS f32x2 ({batch0,batch1}) unit offsets.  16B-slot = (units/2) mod 8.
#define XC   0      // C [2][96]: 0-19 x, 20-69 h1, 70-95 pad0
#define CS   96     // C stride (96/2 % 8 == 0 -> slots parity-invariant)
#define XH2  192    // h2 [2][64]; chunk slots 0,5
#define XH3  322    // h3 [2][64]; chunk slots 1,6
#define SMSZ 450

typedef float f32x2 __attribute__((ext_vector_type(2)));
typedef float f32x4 __attribute__((ext_vector_type(4)));

// d += broadcast(w.lo)*u  /  d += broadcast(w.hi)*u   (VOP3P op_sel)
__device__ __forceinline__ void pkfma_lo(f32x2& d, f32x2 w, f32x2 u) {
    asm("v_pk_fma_f32 %0, %1, %2, %0 op_sel:[0,0,0] op_sel_hi:[0,1,1]"
        : "+v"(d) : "v"(w), "v"(u));
}
__device__ __forceinline__ void pkfma_hi(f32x2& d, f32x2 w, f32x2 u) {
    asm("v_pk_fma_f32 %0, %1, %2, %0 op_sel:[1,0,0] op_sel_hi:[1,1,1]"
        : "+v"(d) : "v"(w), "v"(u));
}
__device__ __forceinline__ void pkfma(f32x2& d, f32x2 a, f32x2 b) {
    asm("v_pk_fma_f32 %0, %1, %2, %0" : "+v"(d) : "v"(a), "v"(b));
}
__device__ __forceinline__ float sigm(float x) {
    return __builtin_amdgcn_rcpf(1.0f + __expf(-x));
}
__device__ __forceinline__ float tanh_f(float x) {
    return fmaf(2.0f, sigm(2.0f * x), -1.0f);
}
__device__ __forceinline__ f32x2 sigm2(f32x2 v, float b) {
    f32x2 r; r.x = sigm(v.x + b); r.y = sigm(v.y + b); return r;
}
__device__ __forceinline__ f32x2 tanh2(f32x2 v, float b) {
    f32x2 r; r.x = tanh_f(v.x + b); r.y = tanh_f(v.y + b); return r;
}
template <int CTRL>   // quad_perm DPP: 0xB1 = lane^1, 0x4E = lane^2
__device__ __forceinline__ f32x2 dpp2(f32x2 v) {
    f32x2 r;
    r.x = __int_as_float(__builtin_amdgcn_mov_dpp(__float_as_int(v.x), CTRL, 0xF, 0xF, true));
    r.y = __int_as_float(__builtin_amdgcn_mov_dpp(__float_as_int(v.y), CTRL, 0xF, 0xF, true));
    return r;
}
__device__ __forceinline__ f32x2 swzx4(f32x2 v) {   // lane ^ 4 (bit-mode)
    f32x2 r;
    r.x = __int_as_float(__builtin_amdgcn_ds_swizzle(__float_as_int(v.x), 0x101F));
    r.y = __int_as_float(__builtin_amdgcn_ds_swizzle(__float_as_int(v.y), 0x101F));
    return r;
}

__global__ __launch_bounds__(512, 2)
__attribute__((amdgpu_waves_per_eu(2, 2)))
void lstm_net_kernel(
    const float* __restrict__ x,
    const float* __restrict__ W1,   const float* __restrict__ b1,
    const float* __restrict__ Wih1, const float* __restrict__ Whh1,
    const float* __restrict__ bih1, const float* __restrict__ bhh1,
    const float* __restrict__ Wih2, const float* __restrict__ Whh2,
    const float* __restrict__ bih2, const float* __restrict__ bhh2,
    const float* __restrict__ Wih3, const float* __restrict__ Whh3,
    const float* __restrict__ bih3, const float* __restrict__ bhh3,
    const float* __restrict__ W2,   const float* __restrict__ b2,
    float* __restrict__ out)
{
    __shared__ __align__(16) f32x2 sm2[SMSZ];

    const int tid = threadIdx.x;
    const int b0  = blockIdx.x * 2;

    for (int i = tid; i < SMSZ; i += 512) sm2[i] = (f32x2){0.f, 0.f};
    __syncthreads();

    f32x2 wv[72];                        // 4 gates x 18 weight pairs
    #pragma unroll
    for (int i = 0; i < 72; i++) wv[i] = (f32x2){0.f, 0.f};
    float bias4[4] = {0.f, 0.f, 0.f, 0.f};
    int   sel = 0, boff = 0, u = 0, loc = 0, ok = 0, sd = 0;
    bool  isOct = false, isL3 = false;
    f32x2 c1 = {0.f, 0.f};               // L1 cell (even L1 lanes)
    f32x2 xs[5];
    #pragma unroll
    for (int i = 0; i < 5; i++) xs[i] = (f32x2){0.f, 0.f};

    if (tid < 400) {                     // L2/L3 octets
        isOct = true;
        u = tid >> 3; loc = tid & 7; isL3 = (loc >= 4);
        const int r = loc & 3, side = r >> 1, chunk = r & 1;
        const float* src = isL3 ? (side ? Whh3 : Wih3) : (side ? Whh2 : Wih2);
        const float* bi  = isL3 ? bih3 : bih2;
        const float* bh  = isL3 ? bhh3 : bhh2;
        const int row4[4] = {u, 50 + u, 100 + u, 150 + u};   // i,f,g,o
        #pragma unroll
        for (int m = 0; m < 4; m++) {
            const bool dead = isL3 && (m == 1);              // f3 dead (c3==0)
            const int row = row4[m];
            #pragma unroll
            for (int i = 0; i < 18; i++) {
                const int k0 = 2 * i, k1 = 2 * i + 1;
                const int d0 = 26 * chunk + k0, d1 = 26 * chunk + k1;
                const float w0 = (!dead && k0 < 26 && d0 < 50) ? src[row * 50 + d0] : 0.f;
                const float w1 = (!dead && k1 < 26 && d1 < 50) ? src[row * 50 + d1] : 0.f;
                wv[m * 18 + i] = (f32x2){w0, w1};
            }
            bias4[m] = dead ? 0.f : bi[row] + bh[row];
        }
        if (!isL3) { sel = side ? 1 : 0; boff = side ? 26 * chunk : 20 + 26 * chunk; }
        else       { sel = side ? 2 : 1; boff = 26 * chunk; }
    } else if (tid < 500) {              // L1 pairs, linear1 folded
        u = (tid - 400) >> 1;
        const int h = tid & 1;           // tid 400 -> abs lane 16: even
        sel = 0; boff = 36 * h;
        const int row4[4] = {u, 50 + u, 100 + u, 150 + u};
        #pragma unroll
        for (int m = 0; m < 4; m++) {
            const int row = row4[m];
            float bs = bih1[row] + bhh1[row];
            for (int j = 0; j < 50; j++) bs = fmaf(Wih1[row * 50 + j], b1[j], bs);
            bias4[m] = bs;
            if (h == 0) {                // concat dims 0-35 = foldX(20)+h1(0-15)
                float a20[20];
                #pragma unroll
                for (int k = 0; k < 20; k++) a20[k] = 0.f;
                for (int j = 0; j < 50; j++) {
                    const float a = Wih1[row * 50 + j];
                    const float* w1r = W1 + j * 20;
                    #pragma unroll
                    for (int k = 0; k < 20; k++) a20[k] = fmaf(a, w1r[k], a20[k]);
                }
                #pragma unroll
                for (int i = 0; i < 18; i++) {
                    const int k0 = 2 * i, k1 = 2 * i + 1;
                    const float w0 = (k0 < 20) ? a20[k0] : Whh1[row * 50 + (k0 - 20)];
                    const float w1 = (k1 < 20) ? a20[k1] : Whh1[row * 50 + (k1 - 20)];
                    wv[m * 18 + i] = (f32x2){w0, w1};
                }
            } else {                     // concat dims 36-69 = h1(16-49)+pad
                #pragma unroll
                for (int i = 0; i < 18; i++) {
                    const int k0 = 2 * i, k1 = 2 * i + 1;
                    const float w0 = (k0 < 34) ? Whh1[row * 50 + 16 + k0] : 0.f;
                    const float w1 = (k1 < 34) ? Whh1[row * 50 + 16 + k1] : 0.f;
                    wv[m * 18 + i] = (f32x2){w0, w1};
                }
            }
        }
    } else if (tid < 508) {              // out-proj
        ok = tid - 500;
        #pragma unroll
        for (int i = 0; i < 26; i++) {
            const int d0 = 2 * i, d1 = 2 * i + 1;
            const float w0 = (d0 < 50) ? W2[ok * 50 + d0] : 0.f;
            const float w1 = (d1 < 50) ? W2[ok * 50 + d1] : 0.f;
            wv[i] = (f32x2){w0, w1};
        }
        bias4[0] = b2[ok];
    } else {                             // x-stage: 4 lanes x dims {sd+4i}
        sd = tid - 508;
        for (int t = 0; t < 3; t++) {    // x(0)->C[0], x(1)->C[1], x(2)->regs
            #pragma unroll
            for (int i = 0; i < 5; i++) {
                const int dim = sd + 4 * i;
                f32x2 v;
                v.x = x[((size_t)b0 * T_SEQ + t) * IN_DIM + dim];
                v.y = x[((size_t)(b0 + 1) * T_SEQ + t) * IN_DIM + dim];
                if (t < 2) sm2[XC + t * CS + dim] = v;
                else       xs[i] = v;
            }
        }
    }
    __syncthreads();

    for (int s = 0; s < T_SEQ + 3; ++s) {
        const int p = s & 1, pm = p ^ 1;

        if (tid < 500) {                 // uniform gate path (octets + L1)
            const int base = ((sel == 0) ? (XC + p * CS)
                            : (sel == 1) ? (XH2 + p * 64)
                                         : (XH3 + pm * 64)) + boff;
            const f32x4* B4 = (const f32x4*)(sm2 + base);
            f32x2 A0 = {0.f,0.f}, A1 = {0.f,0.f}, A2 = {0.f,0.f}, A3 = {0.f,0.f};
            #pragma unroll
            for (int i = 0; i < 18; i++) {
                const f32x4 uu = B4[i];
                const f32x2 ul = uu.lo, uh = uu.hi;
                pkfma_lo(A0, wv[i],      ul); pkfma_hi(A0, wv[i],      uh);
                pkfma_lo(A1, wv[18 + i], ul); pkfma_hi(A1, wv[18 + i], uh);
                pkfma_lo(A2, wv[36 + i], ul); pkfma_hi(A2, wv[36 + i], uh);
                pkfma_lo(A3, wv[54 + i], ul); pkfma_hi(A3, wv[54 + i], uh);
            }
            A0 += dpp2<0xB1>(A0); A1 += dpp2<0xB1>(A1);
            A2 += dpp2<0xB1>(A2); A3 += dpp2<0xB1>(A3);
            if (isOct) {                 // octets: full quad allreduce
                A0 += dpp2<0x4E>(A0); A1 += dpp2<0x4E>(A1);
                A2 += dpp2<0x4E>(A2); A3 += dpp2<0x4E>(A3);
            }
            const f32x2 ii = sigm2(A0, bias4[0]);
            const f32x2 ff = sigm2(A1, bias4[1]);
            const f32x2 gg = tanh2(A2, bias4[2]);
            const f32x2 oo = sigm2(A3, bias4[3]);
            f32x2 P = ii * gg;

            if (isOct) {
                const bool valid3 = (s >= 2) && (s < T_SEQ + 2);
                f32x2 ps = P;
                if (isL3 && !valid3) ps = (f32x2){0.f, 0.f};
                const f32x2 t4 = swzx4(ps);          // L2 lanes receive P3
                if (loc == 0) {                      // L2 combine, t2 = s-1
                    if (s >= 1 && s <= T_SEQ) {
                        f32x2 c2 = P;                // P2
                        pkfma(c2, ff, t4);           // c2 = P2 + f2*P3
                        f32x2 hh;
                        hh.x = oo.x * tanh_f(c2.x);
                        hh.y = oo.y * tanh_f(c2.y);
                        sm2[XH2 + pm * 64 + u] = hh; // slot t2&1 = pm
                    }
                } else if (loc == 4) {               // L3 combine, t3 = s-2
                    if (valid3) {
                        f32x2 hh;
                        hh.x = oo.x * tanh_f(P.x);   // c3==0: cell = i3*g3
                        hh.y = oo.y * tanh_f(P.y);
                        sm2[XH3 + p * 64 + u] = hh;  // slot t3&1 = p
                    }
                }
            } else {                                 // L1 combine, t1 = s
                if ((tid & 1) == 0 && s < T_SEQ) {
                    f32x2 cn = P;
                    pkfma(cn, ff, c1);               // cn = i*g + f*c1
                    c1 = cn;
                    f32x2 hh;
                    hh.x = oo.x * tanh_f(c1.x);
                    hh.y = oo.y * tanh_f(c1.y);
                    sm2[XC + pm * CS + 20 + u] = hh; // consumer-parity slot
                }
            }
        } else if (tid < 508) {          // out, t = s-3
            if (s >= 3) {
                const int t = s - 3;
                const f32x4* H4 = (const f32x4*)(sm2 + XH3 + pm * 64);
                f32x2 a0 = {0.f, 0.f}, a1 = {0.f, 0.f};
                #pragma unroll
                for (int i = 0; i < 26; i++) {
                    const f32x4 uu = H4[i];
                    pkfma_lo(a0, wv[i], uu.lo);
                    pkfma_hi(a1, wv[i], uu.hi);
                }
                const f32x2 acc = a0 + a1;
                out[((size_t)b0 * T_SEQ + t) * OUT_DIM + ok]       = acc.x + bias4[0];
                out[((size_t)(b0 + 1) * T_SEQ + t) * OUT_DIM + ok] = acc.y + bias4[0];
            }
        } else {                         // x-stage
            if (s >= 1 && s + 1 < T_SEQ) {           // commit x(s+1) -> C[pm]
                #pragma unroll
                for (int i = 0; i < 5; i++)
                    sm2[XC + pm * CS + sd + 4 * i] = xs[i];
            }
            if (s + 2 < T_SEQ) {                     // load x(s+2) -> regs
                const int t = s + 2;
                #pragma unroll
                for (int i = 0; i < 5; i++) {
                    const int dim = sd + 4 * i;
                    xs[i].x = x[((size_t)b0 * T_SEQ + t) * IN_DIM + dim];
                    xs[i].y = x[((size_t)(b0 + 1) * T_SEQ + t) * IN_DIM + dim];
                }
            }
        }
        __syncthreads();
    }
}

extern "C" void kernel_launch(void* const* d_in, const int* in_sizes, int n_in,
                              void* d_out, int out_size, void* d_ws, size_t ws_size,
                              hipStream_t stream) {
    const float* x    = (const float*)d_in[0];
    const float* W1   = (const float*)d_in[1];
    const float* b1   = (const float*)d_in[2];
    const float* Wih1 = (const float*)d_in[3];
    const float* Whh1 = (const float*)d_in[4];
    const float* bih1 = (const float*)d_in[5];
    const float* bhh1 = (const float*)d_in[6];
    const float* Wih2 = (const float*)d_in[7];
    const float* Whh2 = (const float*)d_in[8];
    const float* bih2 = (const float*)d_in[9];
    const float* bhh2 = (const float*)d_in[10];
    const float* Wih3 = (const float*)d_in[11];
    const float* Whh3 = (const float*)d_in[12];
    const float* bih3 = (const float*)d_in[13];
    const float* bhh3 = (const float*)d_in[14];
    const float* W2   = (const float*)d_in[15];
    const float* b2   = (const float*)d_in[16];
    float* out = (float*)d_out;

    dim3 grid(256), block(512);
    lstm_net_kernel<<<grid, block, 0, stream>>>(
        x, W1, b1, Wih1, Whh1, bih1, bhh1, Wih2, Whh2, bih2, bhh2,
        Wih3, Whh3, bih3, bhh3, W2, b2, out);
}